// Round 8
// baseline (200.201 us; speedup 1.0000x reference)
//
#include <hip/hip_runtime.h>

#define NN 100000
#define NE 1600000
#define C 32

#define SHIFT 8
#define BINW 256                              // nodes per bin
#define NBIN ((NN + BINW - 1) / BINW)         // 391
#define EPB 2048                              // edges per block (binning)
#define NCHK ((NE + EPB - 1) / EPB)           // 782 chunks = k_bin blocks
#define SLACK 32                              // slots per (chunk,bin); lambda=5.24, P(ovf)~7e-7
#define CAPT (NCHK * SLACK)                   // 25024 tmp slots per bin
#define SCAP 5120                             // LDS sorted-list capacity (4096+16sigma)

__device__ __forceinline__ unsigned bf16rne(float f) {
    unsigned u = __float_as_uint(f);
    return (u + 0x7fffu + ((u >> 16) & 1u)) >> 16;
}
__device__ __forceinline__ float blo(unsigned u) { return __uint_as_float(u << 16); }
__device__ __forceinline__ float bhi(unsigned u) { return __uint_as_float(u & 0xffff0000u); }

// ---------------- kernels ----------------

// zero per-node degree (ws is poisoned each iter)
__global__ __launch_bounds__(256) void k_init(int* __restrict__ deg) {
    int i = blockIdx.x * 256 + threadIdx.x;
    if (i < NN) deg[i] = 0;
}

// single-pass scatter into chunk-partitioned bins + global per-node degree.
// Block b statically owns slots [bin*CAPT + b*32, +32) of every bin. 782
// blocks (~3/CU) so the deg atomics + scattered stores overlap across waves
// (round-7 lesson: at 196 blocks the same atomics added +30us).
__global__ __launch_bounds__(256) void k_bin(const int* __restrict__ ei,
                                             int* __restrict__ tmp,
                                             int* __restrict__ cfill,
                                             int* __restrict__ deg) {
    __shared__ int lcur[NBIN];
    int b = blockIdx.x, t = threadIdx.x;
    for (int i = t; i < NBIN; i += 256) lcur[i] = i * CAPT + (b << 5);
    __syncthreads();
    int e0 = b * EPB, e1 = min(e0 + EPB, NE);   // windows %4 == 0
    const int4* src4 = (const int4*)ei;
    const int4* col4 = (const int4*)(ei + NE);
    for (int q = (e0 >> 2) + t; q < (e1 >> 2); q += 256) {
        int4 s = src4[q];
        int4 c = col4[q];
        int p0 = atomicAdd(&lcur[c.x >> SHIFT], 1);
        tmp[p0] = (s.x << SHIFT) | (c.x & (BINW - 1));
        int p1 = atomicAdd(&lcur[c.y >> SHIFT], 1);
        tmp[p1] = (s.y << SHIFT) | (c.y & (BINW - 1));
        int p2 = atomicAdd(&lcur[c.z >> SHIFT], 1);
        tmp[p2] = (s.z << SHIFT) | (c.z & (BINW - 1));
        int p3 = atomicAdd(&lcur[c.w >> SHIFT], 1);
        tmp[p3] = (s.w << SHIFT) | (c.w & (BINW - 1));
        atomicAdd(&deg[c.x], 1);                // fire-and-forget L2 atomics
        atomicAdd(&deg[c.y], 1);
        atomicAdd(&deg[c.z], 1);
        atomicAdd(&deg[c.w], 1);
    }
    __syncthreads();
    // [b][i] layout: coalesced write here (round-7's [i][b] strided store
    // was ~20MB of write-amplification); placeAgg's read is L2-hot.
    for (int i = t; i < NBIN; i += 256)
        cfill[b * NBIN + i] = lcur[i] - (i * CAPT + (b << 5));
}

// h' = bf16( dinv * (x @ W^T) ), packed 2 channels/uint -> 64B rows.
__global__ __launch_bounds__(256) void k_linear(const float* __restrict__ x,
                                                const float* __restrict__ W,
                                                const int* __restrict__ deg,
                                                unsigned* __restrict__ hu) {
    __shared__ float Ws[C][C + 1];
    __shared__ float xs[16][C];
    int t = threadIdx.x;
    for (int i = t; i < C * C; i += 256)
        Ws[i / C][i % C] = W[i];

    int node0 = blockIdx.x * 16;
#pragma unroll
    for (int i = t; i < 16 * C; i += 256) {
        int idx = node0 * C + i;     // coalesced load of 16 rows
        xs[i >> 5][i & 31] = (idx < NN * C) ? x[idx] : 0.0f;
    }
    __syncthreads();
    int lnode = t >> 4, m = t & 15;
    int node = node0 + lnode;
    if (node < NN) {
        float a0 = 0.0f, a1 = 0.0f;
#pragma unroll
        for (int k = 0; k < C; ++k) {
            float xv = xs[lnode][k];
            a0 += xv * Ws[2 * m][k];
            a1 += xv * Ws[2 * m + 1][k];
        }
        float d = rsqrtf(1.0f + (float)deg[node]);   // deg incl. self-loop
        hu[node * 16 + m] = bf16rne(a0 * d) | (bf16rne(a1 * d) << 16);
    }
}

// fused place+aggregate: one block per bin. Count gapped segment -> wave
// scan -> place sorted edge list in LDS -> 8-lane-group-per-node register
// gather (no shuffles, no srt/off/dinv globals, one dispatch).
#define AGG_T 1024
__global__ __launch_bounds__(AGG_T) void k_placeAgg(const int* __restrict__ cfill,
                                                    const int* __restrict__ tmp,
                                                    const uint2* __restrict__ hu2,
                                                    const float* __restrict__ b,
                                                    float* __restrict__ out) {
    __shared__ int ccnt[NCHK];
    __shared__ int lcnt[BINW];
    __shared__ int lbase[BINW];
    __shared__ int lcur[BINW];
    __shared__ int lsort[SCAP];               // ~20.5KB; total LDS ~27KB
    __shared__ int wtot[4], wbase[4];
    int bin = blockIdx.x, t = threadIdx.x;
    if (t < NCHK) ccnt[t] = cfill[t * NBIN + bin];   // strided, L2-hot 1.2MB
    if (t < BINW) lcnt[t] = 0;
    __syncthreads();
    int gb = bin * CAPT;
    // phase A: count valid slots of the gapped segment (SLACK=32 -> shifts)
    for (int s = t; s < CAPT; s += AGG_T) {
        if ((s & 31) < ccnt[s >> 5])
            atomicAdd(&lcnt[tmp[gb + s] & (BINW - 1)], 1);
    }
    __syncthreads();
    // phase B: exclusive scan of 256 counts (threads 0..255 = waves 0..3)
    int lane = t & 63, w4 = t >> 6;
    int cv = 0, v = 0;
    if (t < BINW) {
        cv = lcnt[t];
        v = cv;
#pragma unroll
        for (int d = 1; d < 64; d <<= 1) {
            int u = __shfl_up(v, d);
            if (lane >= d) v += u;
        }
        if (lane == 63) wtot[w4] = v;
    }
    __syncthreads();
    if (t == 0) {
        int r = 0;
#pragma unroll
        for (int k = 0; k < 4; ++k) { wbase[k] = r; r += wtot[k]; }
    }
    __syncthreads();
    if (t < BINW) {
        int loc = wbase[w4] + v - cv;          // exclusive local offset
        lbase[t] = loc;
        lcur[t] = loc;
    }
    __syncthreads();
    // phase C: place into LDS sorted list (tmp re-read is L2-hot)
    for (int s = t; s < CAPT; s += AGG_T) {
        if ((s & 31) < ccnt[s >> 5]) {
            int e = tmp[gb + s];
            int pos = atomicAdd(&lcur[e & (BINW - 1)], 1);
            lsort[pos] = e >> SHIFT;
        }
    }
    __syncthreads();
    // phase D: gather. 8-lane group per node; edges contiguous in lsort.
    int G = t >> 3, m = t & 7;                 // 128 groups, channels 4m..4m+3
#pragma unroll
    for (int rr = 0; rr < 2; ++rr) {
        int loc = G + rr * 128;
        int node = (bin << SHIFT) + loc;
        int beg = lbase[loc], cnt = lcnt[loc];
        float s0 = 0.0f, s1 = 0.0f, s2 = 0.0f, s3 = 0.0f;
        int j = beg, jend = beg + cnt;
        for (; j + 3 < jend; j += 4) {         // 4 rows in flight per group
            int r0 = lsort[j], r1 = lsort[j + 1], r2 = lsort[j + 2], r3 = lsort[j + 3];
            uint2 u0 = hu2[r0 * 8 + m];
            uint2 u1 = hu2[r1 * 8 + m];
            uint2 u2 = hu2[r2 * 8 + m];
            uint2 u3 = hu2[r3 * 8 + m];
            s0 += blo(u0.x); s1 += bhi(u0.x); s2 += blo(u0.y); s3 += bhi(u0.y);
            s0 += blo(u1.x); s1 += bhi(u1.x); s2 += blo(u1.y); s3 += bhi(u1.y);
            s0 += blo(u2.x); s1 += bhi(u2.x); s2 += blo(u2.y); s3 += bhi(u2.y);
            s0 += blo(u3.x); s1 += bhi(u3.x); s2 += blo(u3.y); s3 += bhi(u3.y);
        }
        for (; j < jend; ++j) {
            uint2 u = hu2[lsort[j] * 8 + m];
            s0 += blo(u.x); s1 += bhi(u.x); s2 += blo(u.y); s3 += bhi(u.y);
        }
        if (node < NN) {
            float dn = rsqrtf(1.0f + (float)cnt);
            uint2 us = hu2[node * 8 + m];      // self-loop row (pre-scaled)
            float4 bb = ((const float4*)b)[m];
            float o0 = bb.x + dn * (s0 + blo(us.x));
            float o1 = bb.y + dn * (s1 + bhi(us.x));
            float o2 = bb.z + dn * (s2 + blo(us.y));
            float o3 = bb.w + dn * (s3 + bhi(us.y));
            ((float4*)out)[node * 8 + m] = make_float4(o0, o1, o2, o3);
        }
    }
}

// ---------------- launch ----------------

extern "C" void kernel_launch(void* const* d_in, const int* in_sizes, int n_in,
                              void* d_out, int out_size, void* d_ws, size_t ws_size,
                              hipStream_t stream) {
    const float* x  = (const float*)d_in[0];
    const int*   ei = (const int*)d_in[1];
    const float* W  = (const float*)d_in[2];
    const float* b  = (const float*)d_in[3];
    float* out = (float*)d_out;

    // ws (~47 MB of 256 MB pool) — no overlays, all buffers distinct
    char* ws = (char*)d_ws;
    size_t o = 0;
    int*      tmp   = (int*)(ws + o);      o += (size_t)NBIN * CAPT * 4;   o = (o + 255) & ~(size_t)255;
    unsigned* hu    = (unsigned*)(ws + o); o += (size_t)NN * 16 * 4;       o = (o + 255) & ~(size_t)255;
    int*      cfill = (int*)(ws + o);      o += (size_t)NCHK * NBIN * 4;   o = (o + 255) & ~(size_t)255;
    int*      deg   = (int*)(ws + o);

    k_init<<<(NN + 255) / 256, 256, 0, stream>>>(deg);
    k_bin<<<NCHK, 256, 0, stream>>>(ei, tmp, cfill, deg);
    k_linear<<<(NN + 15) / 16, 256, 0, stream>>>(x, W, deg, hu);
    k_placeAgg<<<NBIN, AGG_T, 0, stream>>>(cfill, tmp, (const uint2*)hu, b, out);
}

// Round 9
// 125.832 us; speedup vs baseline: 1.5910x; 1.5910x over previous
//
#include <hip/hip_runtime.h>

#define NN 100000
#define NE 1600000
#define C 32

#define SHIFT 8
#define BINW 256                              // nodes per bin
#define NBIN ((NN + BINW - 1) / BINW)         // 391
#define EPB 8192                              // edges per block (binning)
#define NCHK ((NE + EPB - 1) / EPB)           // 196 chunks = k_bin blocks
#define SLACK 56                              // slots per (chunk,bin); lambda~21, 7.7 sigma
#define CAPT (NCHK * SLACK)                   // 10976 tmp slots per bin (%4==0)
#define SCAP 5120                             // LDS sorted-list capacity (4096+16sigma)

__device__ __forceinline__ unsigned bf16rne(float f) {
    unsigned u = __float_as_uint(f);
    return (u + 0x7fffu + ((u >> 16) & 1u)) >> 16;
}
__device__ __forceinline__ float blo(unsigned u) { return __uint_as_float(u << 16); }
__device__ __forceinline__ float bhi(unsigned u) { return __uint_as_float(u & 0xffff0000u); }

// ---------------- kernels ----------------

// single-pass scatter into chunk-partitioned bins (R6's proven shape: no
// histogram pass, no scans, no global atomics of ANY kind). Block b owns
// slots [bin*CAPT + b*SLACK, +SLACK) of every bin.
__global__ __launch_bounds__(256) void k_bin(const int* __restrict__ ei,
                                             int* __restrict__ tmp,
                                             int* __restrict__ cfill) {
    __shared__ int lcur[NBIN];
    int b = blockIdx.x, t = threadIdx.x;
    for (int i = t; i < NBIN; i += 256) lcur[i] = i * CAPT + b * SLACK;
    __syncthreads();
    int e0 = b * EPB, e1 = min(e0 + EPB, NE);   // windows %4 == 0
    const int4* src4 = (const int4*)ei;
    const int4* col4 = (const int4*)(ei + NE);
    for (int q = (e0 >> 2) + t; q < (e1 >> 2); q += 256) {
        int4 s = src4[q];
        int4 c = col4[q];
        int p0 = atomicAdd(&lcur[c.x >> SHIFT], 1);
        tmp[p0] = (s.x << SHIFT) | (c.x & (BINW - 1));
        int p1 = atomicAdd(&lcur[c.y >> SHIFT], 1);
        tmp[p1] = (s.y << SHIFT) | (c.y & (BINW - 1));
        int p2 = atomicAdd(&lcur[c.z >> SHIFT], 1);
        tmp[p2] = (s.z << SHIFT) | (c.z & (BINW - 1));
        int p3 = atomicAdd(&lcur[c.w >> SHIFT], 1);
        tmp[p3] = (s.w << SHIFT) | (c.w & (BINW - 1));
    }
    __syncthreads();
    for (int i = t; i < NBIN; i += 256)         // [b][i]: coalesced write
        cfill[b * NBIN + i] = lcur[i] - (i * CAPT + b * SLACK);
}

// per-bin degree by LDS histogram (native int ds_add; NO global atomics,
// no zero-init kernel). One int4 walk of the bin's gapped segment (L2-hot:
// tmp was just written). Writes deg (for placeAgg's scan) + dinv (for
// linear's prescale) wholesale.
__global__ __launch_bounds__(1024) void k_deg(const int* __restrict__ cfill,
                                              const int* __restrict__ tmp,
                                              int* __restrict__ deg,
                                              float* __restrict__ dinv) {
    __shared__ int ccnt[NCHK];
    __shared__ int cnt[BINW];
    int bin = blockIdx.x, t = threadIdx.x;
    if (t < NCHK) ccnt[t] = cfill[t * NBIN + bin];
    if (t < BINW) cnt[t] = 0;
    __syncthreads();
    const int4* tp4 = (const int4*)tmp + bin * (CAPT >> 2);
    for (int q = t; q < (CAPT >> 2); q += 1024) {
        int4 v = tp4[q];
        int s = q << 2;
        int chunk = s / SLACK;                 // magic-mul division
        int off = s - chunk * SLACK;           // 4 consecutive slots cross
        if (off < ccnt[chunk]) atomicAdd(&cnt[v.x & (BINW - 1)], 1);
        if (++off == SLACK) { off = 0; ++chunk; }   // <=1 boundary per int4
        if (off < ccnt[chunk]) atomicAdd(&cnt[v.y & (BINW - 1)], 1);
        if (++off == SLACK) { off = 0; ++chunk; }
        if (off < ccnt[chunk]) atomicAdd(&cnt[v.z & (BINW - 1)], 1);
        if (++off == SLACK) { off = 0; ++chunk; }
        if (off < ccnt[chunk]) atomicAdd(&cnt[v.w & (BINW - 1)], 1);
    }
    __syncthreads();
    if (t < BINW) {
        int node = (bin << SHIFT) + t;
        if (node < NN) {
            int cv = cnt[t];
            deg[node] = cv;
            dinv[node] = rsqrtf(1.0f + (float)cv);   // incl. self-loop
        }
    }
}

// h' = bf16( dinv * (x @ W^T) ), packed 2 channels/uint -> 64B rows.
__global__ __launch_bounds__(256) void k_linear(const float* __restrict__ x,
                                                const float* __restrict__ W,
                                                const float* __restrict__ dinv,
                                                unsigned* __restrict__ hu) {
    __shared__ float Ws[C][C + 1];
    __shared__ float xs[16][C];
    int t = threadIdx.x;
    for (int i = t; i < C * C; i += 256)
        Ws[i / C][i % C] = W[i];

    int node0 = blockIdx.x * 16;
#pragma unroll
    for (int i = t; i < 16 * C; i += 256) {
        int idx = node0 * C + i;     // coalesced load of 16 rows
        xs[i >> 5][i & 31] = (idx < NN * C) ? x[idx] : 0.0f;
    }
    __syncthreads();
    int lnode = t >> 4, m = t & 15;
    int node = node0 + lnode;
    if (node < NN) {
        float a0 = 0.0f, a1 = 0.0f;
#pragma unroll
        for (int k = 0; k < C; ++k) {
            float xv = xs[lnode][k];
            a0 += xv * Ws[2 * m][k];
            a1 += xv * Ws[2 * m + 1][k];
        }
        float d = dinv[node];
        hu[node * 16 + m] = bf16rne(a0 * d) | (bf16rne(a1 * d) << 16);
    }
}

// fused place+aggregate: one block per bin. Reads deg (no counting pass) ->
// scan -> place sorted edge list in LDS (one walk) -> 8-lane-group-per-node
// register gather.
#define AGG_T 1024
__global__ __launch_bounds__(AGG_T) void k_placeAgg(const int* __restrict__ cfill,
                                                    const int* __restrict__ tmp,
                                                    const int* __restrict__ deg,
                                                    const uint2* __restrict__ hu2,
                                                    const float* __restrict__ b,
                                                    float* __restrict__ out) {
    __shared__ int ccnt[NCHK];
    __shared__ int dg[BINW];
    __shared__ int lbase[BINW];
    __shared__ int lcur[BINW];
    __shared__ int lsort[SCAP];               // ~20.5KB; total LDS ~24.5KB
    __shared__ int wtot[4], wbase[4];
    int bin = blockIdx.x, t = threadIdx.x;
    if (t < NCHK) ccnt[t] = cfill[t * NBIN + bin];
    if (t < BINW) {
        int node = (bin << SHIFT) + t;
        dg[t] = (node < NN) ? deg[node] : 0;   // coalesced, L2-hot
    }
    __syncthreads();
    // scan of 256 degs (threads 0..255 = waves 0..3)
    int lane = t & 63, w4 = t >> 6;
    int cv = 0, v = 0;
    if (t < BINW) {
        cv = dg[t];
        v = cv;
#pragma unroll
        for (int d = 1; d < 64; d <<= 1) {
            int u = __shfl_up(v, d);
            if (lane >= d) v += u;
        }
        if (lane == 63) wtot[w4] = v;
    }
    __syncthreads();
    if (t == 0) {
        int r = 0;
#pragma unroll
        for (int k = 0; k < 4; ++k) { wbase[k] = r; r += wtot[k]; }
    }
    __syncthreads();
    if (t < BINW) {
        int loc = wbase[w4] + v - cv;          // exclusive local offset
        lbase[t] = loc;
        lcur[t] = loc;
    }
    __syncthreads();
    // place: one int4 walk of the gapped segment into LDS sorted list
    const int4* tp4 = (const int4*)tmp + bin * (CAPT >> 2);
    for (int q = t; q < (CAPT >> 2); q += AGG_T) {
        int4 e = tp4[q];
        int s = q << 2;
        int chunk = s / SLACK;
        int off = s - chunk * SLACK;
        if (off < ccnt[chunk]) lsort[atomicAdd(&lcur[e.x & (BINW - 1)], 1)] = e.x >> SHIFT;
        if (++off == SLACK) { off = 0; ++chunk; }
        if (off < ccnt[chunk]) lsort[atomicAdd(&lcur[e.y & (BINW - 1)], 1)] = e.y >> SHIFT;
        if (++off == SLACK) { off = 0; ++chunk; }
        if (off < ccnt[chunk]) lsort[atomicAdd(&lcur[e.z & (BINW - 1)], 1)] = e.z >> SHIFT;
        if (++off == SLACK) { off = 0; ++chunk; }
        if (off < ccnt[chunk]) lsort[atomicAdd(&lcur[e.w & (BINW - 1)], 1)] = e.w >> SHIFT;
    }
    __syncthreads();
    // gather: 8-lane group per node; edges contiguous in lsort.
    int G = t >> 3, m = t & 7;                 // 128 groups, channels 4m..4m+3
#pragma unroll
    for (int rr = 0; rr < 2; ++rr) {
        int loc = G + rr * 128;
        int node = (bin << SHIFT) + loc;
        int beg = lbase[loc], cnt = dg[loc];
        float s0 = 0.0f, s1 = 0.0f, s2 = 0.0f, s3 = 0.0f;
        int j = beg, jend = beg + cnt;
        for (; j + 3 < jend; j += 4) {         // 4 rows in flight per group
            int r0 = lsort[j], r1 = lsort[j + 1], r2 = lsort[j + 2], r3 = lsort[j + 3];
            uint2 u0 = hu2[r0 * 8 + m];
            uint2 u1 = hu2[r1 * 8 + m];
            uint2 u2 = hu2[r2 * 8 + m];
            uint2 u3 = hu2[r3 * 8 + m];
            s0 += blo(u0.x); s1 += bhi(u0.x); s2 += blo(u0.y); s3 += bhi(u0.y);
            s0 += blo(u1.x); s1 += bhi(u1.x); s2 += blo(u1.y); s3 += bhi(u1.y);
            s0 += blo(u2.x); s1 += bhi(u2.x); s2 += blo(u2.y); s3 += bhi(u2.y);
            s0 += blo(u3.x); s1 += bhi(u3.x); s2 += blo(u3.y); s3 += bhi(u3.y);
        }
        for (; j < jend; ++j) {
            uint2 u = hu2[lsort[j] * 8 + m];
            s0 += blo(u.x); s1 += bhi(u.x); s2 += blo(u.y); s3 += bhi(u.y);
        }
        if (node < NN) {
            float dn = rsqrtf(1.0f + (float)cnt);
            uint2 us = hu2[node * 8 + m];      // self-loop row (pre-scaled)
            float4 bb = ((const float4*)b)[m];
            float o0 = bb.x + dn * (s0 + blo(us.x));
            float o1 = bb.y + dn * (s1 + bhi(us.x));
            float o2 = bb.z + dn * (s2 + blo(us.y));
            float o3 = bb.w + dn * (s3 + bhi(us.y));
            ((float4*)out)[node * 8 + m] = make_float4(o0, o1, o2, o3);
        }
    }
}

// ---------------- launch ----------------

extern "C" void kernel_launch(void* const* d_in, const int* in_sizes, int n_in,
                              void* d_out, int out_size, void* d_ws, size_t ws_size,
                              hipStream_t stream) {
    const float* x  = (const float*)d_in[0];
    const int*   ei = (const int*)d_in[1];
    const float* W  = (const float*)d_in[2];
    const float* b  = (const float*)d_in[3];
    float* out = (float*)d_out;

    // ws (~25 MB of 256 MB pool) — no overlays, all buffers distinct
    char* ws = (char*)d_ws;
    size_t o = 0;
    int*      tmp   = (int*)(ws + o);      o += (size_t)NBIN * CAPT * 4;   o = (o + 255) & ~(size_t)255;
    unsigned* hu    = (unsigned*)(ws + o); o += (size_t)NN * 16 * 4;       o = (o + 255) & ~(size_t)255;
    int*      cfill = (int*)(ws + o);      o += (size_t)NCHK * NBIN * 4;   o = (o + 255) & ~(size_t)255;
    int*      deg   = (int*)(ws + o);      o += (size_t)NN * 4;            o = (o + 255) & ~(size_t)255;
    float*    dinv  = (float*)(ws + o);

    k_bin<<<NCHK, 256, 0, stream>>>(ei, tmp, cfill);
    k_deg<<<NBIN, 1024, 0, stream>>>(cfill, tmp, deg, dinv);
    k_linear<<<(NN + 15) / 16, 256, 0, stream>>>(x, W, dinv, hu);
    k_placeAgg<<<NBIN, AGG_T, 0, stream>>>(cfill, tmp, deg, (const uint2*)hu, b, out);
}

// Round 10
// 125.592 us; speedup vs baseline: 1.5941x; 1.0019x over previous
//
#include <hip/hip_runtime.h>

#define NN 100000
#define NE 1600000
#define C 32

#define SHIFT 8
#define BINW 256                              // nodes per bin
#define NBIN ((NN + BINW - 1) / BINW)         // 391
#define EPB 8192                              // edges per block (binning)
#define NCHK ((NE + EPB - 1) / EPB)           // 196 chunks = k_bin blocks
#define SLACK 56                              // slots per (chunk,bin); lambda~21, 7.7 sigma
#define CAPT (NCHK * SLACK)                   // 10976 tmp slots per bin (%8==0)
#define SCAP 5120                             // LDS sorted-list capacity (4096+16sigma)

__device__ __forceinline__ unsigned bf16rne(float f) {
    unsigned u = __float_as_uint(f);
    return (u + 0x7fffu + ((u >> 16) & 1u)) >> 16;
}
__device__ __forceinline__ float blo(unsigned u) { return __uint_as_float(u << 16); }
__device__ __forceinline__ float bhi(unsigned u) { return __uint_as_float(u & 0xffff0000u); }

// ---------------- kernels ----------------

// single-pass scatter into chunk-partitioned bins. Block b statically owns
// slots [bin*CAPT + b*SLACK, +SLACK) of every bin. 1024 threads/block:
// same 196 blocks (partition density is fixed — R8 lesson) but 4x the
// waves/CU so scattered-store + load latency overlaps (R9's k_bin had
// <1 wave/SIMD chip-wide).
__global__ __launch_bounds__(1024) void k_bin(const int* __restrict__ ei,
                                              int* __restrict__ tmp,
                                              int* __restrict__ cfill) {
    __shared__ int lcur[NBIN];
    int b = blockIdx.x, t = threadIdx.x;
    if (t < NBIN) lcur[t] = t * CAPT + b * SLACK;
    __syncthreads();
    int e0 = b * EPB, e1 = min(e0 + EPB, NE);   // windows %4 == 0
    const int4* src4 = (const int4*)ei;
    const int4* col4 = (const int4*)(ei + NE);
    for (int q = (e0 >> 2) + t; q < (e1 >> 2); q += 1024) {
        int4 s = src4[q];
        int4 c = col4[q];
        int p0 = atomicAdd(&lcur[c.x >> SHIFT], 1);
        tmp[p0] = (s.x << SHIFT) | (c.x & (BINW - 1));
        int p1 = atomicAdd(&lcur[c.y >> SHIFT], 1);
        tmp[p1] = (s.y << SHIFT) | (c.y & (BINW - 1));
        int p2 = atomicAdd(&lcur[c.z >> SHIFT], 1);
        tmp[p2] = (s.z << SHIFT) | (c.z & (BINW - 1));
        int p3 = atomicAdd(&lcur[c.w >> SHIFT], 1);
        tmp[p3] = (s.w << SHIFT) | (c.w & (BINW - 1));
    }
    __syncthreads();
    if (t < NBIN)                               // [b][i]: coalesced write
        cfill[b * NBIN + t] = lcur[t] - (t * CAPT + b * SLACK);
}

// fused degree + linear: one block per bin. Stage x-rows + W while the
// histogram walk of the bin's gapped segment runs (int4, L2-hot), then
// hu = bf16( rsqrt(1+cnt) * (x @ W^T) ) straight from in-LDS counts.
// deg written (400KB) only for placeAgg's scan; dinv never materialized.
__global__ __launch_bounds__(1024) void k_degLin(const int* __restrict__ cfill,
                                                 const int* __restrict__ tmp,
                                                 const float* __restrict__ x,
                                                 const float* __restrict__ W,
                                                 int* __restrict__ deg,
                                                 unsigned* __restrict__ hu) {
    __shared__ int ccnt[NCHK];
    __shared__ int cnt[BINW];
    __shared__ float Ws[C][C + 1];
    __shared__ float xs[BINW][C];              // 32KB; total LDS ~38.8KB
    int bin = blockIdx.x, t = threadIdx.x;
    if (t < NCHK) ccnt[t] = cfill[t * NBIN + bin];
    if (t < BINW) cnt[t] = 0;
    Ws[t >> 5][t & 31] = W[t];                 // C*C == 1024 exactly
    for (int i = t; i < BINW * C; i += 1024) {
        int idx = (bin << SHIFT) * C + i;      // coalesced 32KB
        xs[i >> 5][i & 31] = (idx < NN * C) ? x[idx] : 0.0f;
    }
    __syncthreads();
    const int4* tp4 = (const int4*)tmp + bin * (CAPT >> 2);
    for (int q = t; q < (CAPT >> 2); q += 1024) {
        int4 v = tp4[q];
        int s = q << 2;
        int chunk = s / SLACK;                 // magic-mul division
        int off = s - chunk * SLACK;           // <=1 boundary per int4
        if (off < ccnt[chunk]) atomicAdd(&cnt[v.x & (BINW - 1)], 1);
        if (++off == SLACK) { off = 0; ++chunk; }
        if (off < ccnt[chunk]) atomicAdd(&cnt[v.y & (BINW - 1)], 1);
        if (++off == SLACK) { off = 0; ++chunk; }
        if (off < ccnt[chunk]) atomicAdd(&cnt[v.z & (BINW - 1)], 1);
        if (++off == SLACK) { off = 0; ++chunk; }
        if (off < ccnt[chunk]) atomicAdd(&cnt[v.w & (BINW - 1)], 1);
    }
    __syncthreads();
    if (t < BINW) {
        int node = (bin << SHIFT) + t;
        if (node < NN) deg[node] = cnt[t];     // for placeAgg's scan
    }
    int m = t & 15, nl0 = t >> 4;              // 64 node-slots x 16 ch-pairs
#pragma unroll
    for (int rep = 0; rep < 4; ++rep) {
        int nl = nl0 + (rep << 6);
        int node = (bin << SHIFT) + nl;
        if (node < NN) {
            float a0 = 0.0f, a1 = 0.0f;
#pragma unroll
            for (int k = 0; k < C; ++k) {
                float xv = xs[nl][k];
                a0 += xv * Ws[2 * m][k];
                a1 += xv * Ws[2 * m + 1][k];
            }
            float d = rsqrtf(1.0f + (float)cnt[nl]);   // incl. self-loop
            hu[node * 16 + m] = bf16rne(a0 * d) | (bf16rne(a1 * d) << 16);
        }
    }
}

// fused place+aggregate: one block per bin. Reads deg (no counting pass) ->
// scan -> place sorted edge list in LDS (one walk) -> 8-lane-group-per-node
// register gather.
#define AGG_T 1024
__global__ __launch_bounds__(AGG_T) void k_placeAgg(const int* __restrict__ cfill,
                                                    const int* __restrict__ tmp,
                                                    const int* __restrict__ deg,
                                                    const uint2* __restrict__ hu2,
                                                    const float* __restrict__ b,
                                                    float* __restrict__ out) {
    __shared__ int ccnt[NCHK];
    __shared__ int dg[BINW];
    __shared__ int lbase[BINW];
    __shared__ int lcur[BINW];
    __shared__ int lsort[SCAP];               // ~20.5KB; total LDS ~24.5KB
    __shared__ int wtot[4], wbase[4];
    int bin = blockIdx.x, t = threadIdx.x;
    if (t < NCHK) ccnt[t] = cfill[t * NBIN + bin];
    if (t < BINW) {
        int node = (bin << SHIFT) + t;
        dg[t] = (node < NN) ? deg[node] : 0;   // coalesced, L2-hot
    }
    __syncthreads();
    // scan of 256 degs (threads 0..255 = waves 0..3)
    int lane = t & 63, w4 = t >> 6;
    int cv = 0, v = 0;
    if (t < BINW) {
        cv = dg[t];
        v = cv;
#pragma unroll
        for (int d = 1; d < 64; d <<= 1) {
            int u = __shfl_up(v, d);
            if (lane >= d) v += u;
        }
        if (lane == 63) wtot[w4] = v;
    }
    __syncthreads();
    if (t == 0) {
        int r = 0;
#pragma unroll
        for (int k = 0; k < 4; ++k) { wbase[k] = r; r += wtot[k]; }
    }
    __syncthreads();
    if (t < BINW) {
        int loc = wbase[w4] + v - cv;          // exclusive local offset
        lbase[t] = loc;
        lcur[t] = loc;
    }
    __syncthreads();
    // place: one int4 walk of the gapped segment into LDS sorted list
    const int4* tp4 = (const int4*)tmp + bin * (CAPT >> 2);
    for (int q = t; q < (CAPT >> 2); q += AGG_T) {
        int4 e = tp4[q];
        int s = q << 2;
        int chunk = s / SLACK;
        int off = s - chunk * SLACK;
        if (off < ccnt[chunk]) lsort[atomicAdd(&lcur[e.x & (BINW - 1)], 1)] = e.x >> SHIFT;
        if (++off == SLACK) { off = 0; ++chunk; }
        if (off < ccnt[chunk]) lsort[atomicAdd(&lcur[e.y & (BINW - 1)], 1)] = e.y >> SHIFT;
        if (++off == SLACK) { off = 0; ++chunk; }
        if (off < ccnt[chunk]) lsort[atomicAdd(&lcur[e.z & (BINW - 1)], 1)] = e.z >> SHIFT;
        if (++off == SLACK) { off = 0; ++chunk; }
        if (off < ccnt[chunk]) lsort[atomicAdd(&lcur[e.w & (BINW - 1)], 1)] = e.w >> SHIFT;
    }
    __syncthreads();
    // gather: 8-lane group per node; edges contiguous in lsort.
    int G = t >> 3, m = t & 7;                 // 128 groups, channels 4m..4m+3
#pragma unroll
    for (int rr = 0; rr < 2; ++rr) {
        int loc = G + rr * 128;
        int node = (bin << SHIFT) + loc;
        int beg = lbase[loc], cnt = dg[loc];
        float s0 = 0.0f, s1 = 0.0f, s2 = 0.0f, s3 = 0.0f;
        int j = beg, jend = beg + cnt;
        for (; j + 3 < jend; j += 4) {         // 4 rows in flight per group
            int r0 = lsort[j], r1 = lsort[j + 1], r2 = lsort[j + 2], r3 = lsort[j + 3];
            uint2 u0 = hu2[r0 * 8 + m];
            uint2 u1 = hu2[r1 * 8 + m];
            uint2 u2 = hu2[r2 * 8 + m];
            uint2 u3 = hu2[r3 * 8 + m];
            s0 += blo(u0.x); s1 += bhi(u0.x); s2 += blo(u0.y); s3 += bhi(u0.y);
            s0 += blo(u1.x); s1 += bhi(u1.x); s2 += blo(u1.y); s3 += bhi(u1.y);
            s0 += blo(u2.x); s1 += bhi(u2.x); s2 += blo(u2.y); s3 += bhi(u2.y);
            s0 += blo(u3.x); s1 += bhi(u3.x); s2 += blo(u3.y); s3 += bhi(u3.y);
        }
        for (; j < jend; ++j) {
            uint2 u = hu2[lsort[j] * 8 + m];
            s0 += blo(u.x); s1 += bhi(u.x); s2 += blo(u.y); s3 += bhi(u.y);
        }
        if (node < NN) {
            float dn = rsqrtf(1.0f + (float)cnt);
            uint2 us = hu2[node * 8 + m];      // self-loop row (pre-scaled)
            float4 bb = ((const float4*)b)[m];
            float o0 = bb.x + dn * (s0 + blo(us.x));
            float o1 = bb.y + dn * (s1 + bhi(us.x));
            float o2 = bb.z + dn * (s2 + blo(us.y));
            float o3 = bb.w + dn * (s3 + bhi(us.y));
            ((float4*)out)[node * 8 + m] = make_float4(o0, o1, o2, o3);
        }
    }
}

// ---------------- launch ----------------

extern "C" void kernel_launch(void* const* d_in, const int* in_sizes, int n_in,
                              void* d_out, int out_size, void* d_ws, size_t ws_size,
                              hipStream_t stream) {
    const float* x  = (const float*)d_in[0];
    const int*   ei = (const int*)d_in[1];
    const float* W  = (const float*)d_in[2];
    const float* b  = (const float*)d_in[3];
    float* out = (float*)d_out;

    // ws (~25 MB of 256 MB pool) — no overlays, all buffers distinct
    char* ws = (char*)d_ws;
    size_t o = 0;
    int*      tmp   = (int*)(ws + o);      o += (size_t)NBIN * CAPT * 4;   o = (o + 255) & ~(size_t)255;
    unsigned* hu    = (unsigned*)(ws + o); o += (size_t)NN * 16 * 4;       o = (o + 255) & ~(size_t)255;
    int*      cfill = (int*)(ws + o);      o += (size_t)NCHK * NBIN * 4;   o = (o + 255) & ~(size_t)255;
    int*      deg   = (int*)(ws + o);

    k_bin<<<NCHK, 1024, 0, stream>>>(ei, tmp, cfill);
    k_degLin<<<NBIN, 1024, 0, stream>>>(cfill, tmp, x, W, deg, hu);
    k_placeAgg<<<NBIN, AGG_T, 0, stream>>>(cfill, tmp, deg, (const uint2*)hu, b, out);
}

// Round 11
// 121.383 us; speedup vs baseline: 1.6493x; 1.0347x over previous
//
#include <hip/hip_runtime.h>

#define NN 100000
#define NE 1600000
#define C 32

#define SHIFT 8
#define BINW 256                              // nodes per bin
#define NBIN ((NN + BINW - 1) / BINW)         // 391
#define EPB 8192                              // edges per block (binning)
#define NCHK ((NE + EPB - 1) / EPB)           // 196 chunks = k_bin blocks
#define SLACK 56                              // slots per (chunk,bin); lambda~21, 7.7 sigma
#define QPC 14                                // int4 quads per chunk cell (SLACK/4)
#define CAPT (NCHK * SLACK)                   // 10976 tmp slots per bin
#define SCAP 5120                             // LDS sorted-list capacity (4096+16sigma)

__device__ __forceinline__ unsigned bf16rne(float f) {
    unsigned u = __float_as_uint(f);
    return (u + 0x7fffu + ((u >> 16) & 1u)) >> 16;
}
__device__ __forceinline__ float blo(unsigned u) { return __uint_as_float(u << 16); }
__device__ __forceinline__ float bhi(unsigned u) { return __uint_as_float(u & 0xffff0000u); }

// ---------------- kernels ----------------

// single-pass scatter into chunk-partitioned bins. Block b statically owns
// slots [bin*CAPT + b*SLACK, +SLACK) of every bin.
__global__ __launch_bounds__(1024) void k_bin(const int* __restrict__ ei,
                                              int* __restrict__ tmp,
                                              int* __restrict__ cfill) {
    __shared__ int lcur[NBIN];
    int b = blockIdx.x, t = threadIdx.x;
    if (t < NBIN) lcur[t] = t * CAPT + b * SLACK;
    __syncthreads();
    int e0 = b * EPB, e1 = min(e0 + EPB, NE);   // windows %4 == 0
    const int4* src4 = (const int4*)ei;
    const int4* col4 = (const int4*)(ei + NE);
    for (int q = (e0 >> 2) + t; q < (e1 >> 2); q += 1024) {
        int4 s = src4[q];
        int4 c = col4[q];
        int p0 = atomicAdd(&lcur[c.x >> SHIFT], 1);
        tmp[p0] = (s.x << SHIFT) | (c.x & (BINW - 1));
        int p1 = atomicAdd(&lcur[c.y >> SHIFT], 1);
        tmp[p1] = (s.y << SHIFT) | (c.y & (BINW - 1));
        int p2 = atomicAdd(&lcur[c.z >> SHIFT], 1);
        tmp[p2] = (s.z << SHIFT) | (c.z & (BINW - 1));
        int p3 = atomicAdd(&lcur[c.w >> SHIFT], 1);
        tmp[p3] = (s.w << SHIFT) | (c.w & (BINW - 1));
    }
    __syncthreads();
    if (t < NBIN)                               // [b][i]: coalesced write
        cfill[b * NBIN + t] = lcur[t] - (t * CAPT + b * SLACK);
}

// fused degree + linear. Quad-skip walk: SLACK%4==0 so each int4 lies in
// one chunk -> validity known BEFORE the load; ~62% of quads never loaded.
__global__ __launch_bounds__(1024) void k_degLin(const int* __restrict__ cfill,
                                                 const int* __restrict__ tmp,
                                                 const float* __restrict__ x,
                                                 const float* __restrict__ W,
                                                 int* __restrict__ deg,
                                                 unsigned* __restrict__ hu) {
    __shared__ int ccnt[NCHK];
    __shared__ int cnt[BINW];
    __shared__ float Ws[C][C + 1];
    __shared__ float xs[BINW][C];              // 32KB; total LDS ~38.8KB
    int bin = blockIdx.x, t = threadIdx.x;
    if (t < NCHK) ccnt[t] = cfill[t * NBIN + bin];
    if (t < BINW) cnt[t] = 0;
    Ws[t >> 5][t & 31] = W[t];                 // C*C == 1024 exactly
    for (int i = t; i < BINW * C; i += 1024) {
        int idx = (bin << SHIFT) * C + i;      // coalesced 32KB
        xs[i >> 5][i & 31] = (idx < NN * C) ? x[idx] : 0.0f;
    }
    __syncthreads();
    const int4* tp4 = (const int4*)tmp + bin * (CAPT >> 2);
    for (int q = t; q < (CAPT >> 2); q += 1024) {
        int chunk = q / QPC;                   // magic-mul division
        int off = (q - chunk * QPC) << 2;
        int fill = ccnt[chunk];
        if (off < fill) {                      // skip empty quads pre-load
            int4 v = tp4[q];
            atomicAdd(&cnt[v.x & (BINW - 1)], 1);
            if (off + 1 < fill) atomicAdd(&cnt[v.y & (BINW - 1)], 1);
            if (off + 2 < fill) atomicAdd(&cnt[v.z & (BINW - 1)], 1);
            if (off + 3 < fill) atomicAdd(&cnt[v.w & (BINW - 1)], 1);
        }
    }
    __syncthreads();
    if (t < BINW) {
        int node = (bin << SHIFT) + t;
        if (node < NN) deg[node] = cnt[t];     // for placeAgg's scan
    }
    int m = t & 15, nl0 = t >> 4;              // 64 node-slots x 16 ch-pairs
#pragma unroll
    for (int rep = 0; rep < 4; ++rep) {
        int nl = nl0 + (rep << 6);
        int node = (bin << SHIFT) + nl;
        if (node < NN) {
            float a0 = 0.0f, a1 = 0.0f;
#pragma unroll
            for (int k = 0; k < C; ++k) {
                float xv = xs[nl][k];
                a0 += xv * Ws[2 * m][k];
                a1 += xv * Ws[2 * m + 1][k];
            }
            float d = rsqrtf(1.0f + (float)cnt[nl]);   // incl. self-loop
            hu[node * 16 + m] = bf16rne(a0 * d) | (bf16rne(a1 * d) << 16);
        }
    }
}

// fused place+aggregate. Place walk quad-skips like degLin. Gather uses
// 4-lane groups x uint4 (16B): one wave-instruction covers 16 edge rows
// (vs 8 with uint2) -> half the vmem issue count for the 1.6M-edge gather.
#define AGG_T 1024
__global__ __launch_bounds__(AGG_T) void k_placeAgg(const int* __restrict__ cfill,
                                                    const int* __restrict__ tmp,
                                                    const int* __restrict__ deg,
                                                    const uint4* __restrict__ hu4,
                                                    const float* __restrict__ b,
                                                    float* __restrict__ out) {
    __shared__ int ccnt[NCHK];
    __shared__ int dg[BINW];
    __shared__ int lbase[BINW];
    __shared__ int lcur[BINW];
    __shared__ int lsort[SCAP];               // ~20.5KB; total LDS ~24.5KB
    __shared__ int wtot[4], wbase[4];
    int bin = blockIdx.x, t = threadIdx.x;
    if (t < NCHK) ccnt[t] = cfill[t * NBIN + bin];
    if (t < BINW) {
        int node = (bin << SHIFT) + t;
        dg[t] = (node < NN) ? deg[node] : 0;   // coalesced, L2-hot
    }
    __syncthreads();
    // scan of 256 degs (threads 0..255 = waves 0..3)
    int lane = t & 63, w4 = t >> 6;
    int cv = 0, v = 0;
    if (t < BINW) {
        cv = dg[t];
        v = cv;
#pragma unroll
        for (int d = 1; d < 64; d <<= 1) {
            int u = __shfl_up(v, d);
            if (lane >= d) v += u;
        }
        if (lane == 63) wtot[w4] = v;
    }
    __syncthreads();
    if (t == 0) {
        int r = 0;
#pragma unroll
        for (int k = 0; k < 4; ++k) { wbase[k] = r; r += wtot[k]; }
    }
    __syncthreads();
    if (t < BINW) {
        int loc = wbase[w4] + v - cv;          // exclusive local offset
        lbase[t] = loc;
        lcur[t] = loc;
    }
    __syncthreads();
    // place: quad-skip int4 walk of the gapped segment into LDS sorted list
    const int4* tp4 = (const int4*)tmp + bin * (CAPT >> 2);
    for (int q = t; q < (CAPT >> 2); q += AGG_T) {
        int chunk = q / QPC;
        int off = (q - chunk * QPC) << 2;
        int fill = ccnt[chunk];
        if (off < fill) {
            int4 e = tp4[q];
            lsort[atomicAdd(&lcur[e.x & (BINW - 1)], 1)] = e.x >> SHIFT;
            if (off + 1 < fill) lsort[atomicAdd(&lcur[e.y & (BINW - 1)], 1)] = e.y >> SHIFT;
            if (off + 2 < fill) lsort[atomicAdd(&lcur[e.z & (BINW - 1)], 1)] = e.z >> SHIFT;
            if (off + 3 < fill) lsort[atomicAdd(&lcur[e.w & (BINW - 1)], 1)] = e.w >> SHIFT;
        }
    }
    __syncthreads();
    // gather: 4-lane group per node (256 groups = all nodes, one pass);
    // lane m covers channels 8m..8m+7 via one uint4 per edge row.
    int g = t >> 2, m = t & 3;
    int beg = lbase[g], cnt = dg[g];
    float s0 = 0.0f, s1 = 0.0f, s2 = 0.0f, s3 = 0.0f;
    float s4 = 0.0f, s5 = 0.0f, s6 = 0.0f, s7 = 0.0f;
    int j = beg, jend = beg + cnt;
    for (; j + 3 < jend; j += 4) {             // 4 rows in flight per lane
        int r0 = lsort[j], r1 = lsort[j + 1], r2 = lsort[j + 2], r3 = lsort[j + 3];
        uint4 u0 = hu4[r0 * 4 + m];
        uint4 u1 = hu4[r1 * 4 + m];
        uint4 u2 = hu4[r2 * 4 + m];
        uint4 u3 = hu4[r3 * 4 + m];
        s0 += blo(u0.x); s1 += bhi(u0.x); s2 += blo(u0.y); s3 += bhi(u0.y);
        s4 += blo(u0.z); s5 += bhi(u0.z); s6 += blo(u0.w); s7 += bhi(u0.w);
        s0 += blo(u1.x); s1 += bhi(u1.x); s2 += blo(u1.y); s3 += bhi(u1.y);
        s4 += blo(u1.z); s5 += bhi(u1.z); s6 += blo(u1.w); s7 += bhi(u1.w);
        s0 += blo(u2.x); s1 += bhi(u2.x); s2 += blo(u2.y); s3 += bhi(u2.y);
        s4 += blo(u2.z); s5 += bhi(u2.z); s6 += blo(u2.w); s7 += bhi(u2.w);
        s0 += blo(u3.x); s1 += bhi(u3.x); s2 += blo(u3.y); s3 += bhi(u3.y);
        s4 += blo(u3.z); s5 += bhi(u3.z); s6 += blo(u3.w); s7 += bhi(u3.w);
    }
    for (; j < jend; ++j) {
        uint4 u = hu4[lsort[j] * 4 + m];
        s0 += blo(u.x); s1 += bhi(u.x); s2 += blo(u.y); s3 += bhi(u.y);
        s4 += blo(u.z); s5 += bhi(u.z); s6 += blo(u.w); s7 += bhi(u.w);
    }
    int node = (bin << SHIFT) + g;
    if (node < NN) {
        float dn = rsqrtf(1.0f + (float)cnt);
        uint4 us = hu4[node * 4 + m];          // self-loop row (pre-scaled)
        float4 b0 = ((const float4*)b)[2 * m];
        float4 b1 = ((const float4*)b)[2 * m + 1];
        float4 o0, o1;
        o0.x = b0.x + dn * (s0 + blo(us.x));
        o0.y = b0.y + dn * (s1 + bhi(us.x));
        o0.z = b0.z + dn * (s2 + blo(us.y));
        o0.w = b0.w + dn * (s3 + bhi(us.y));
        o1.x = b1.x + dn * (s4 + blo(us.z));
        o1.y = b1.y + dn * (s5 + bhi(us.z));
        o1.z = b1.z + dn * (s6 + blo(us.w));
        o1.w = b1.w + dn * (s7 + bhi(us.w));
        ((float4*)out)[node * 8 + 2 * m] = o0;
        ((float4*)out)[node * 8 + 2 * m + 1] = o1;
    }
}

// ---------------- launch ----------------

extern "C" void kernel_launch(void* const* d_in, const int* in_sizes, int n_in,
                              void* d_out, int out_size, void* d_ws, size_t ws_size,
                              hipStream_t stream) {
    const float* x  = (const float*)d_in[0];
    const int*   ei = (const int*)d_in[1];
    const float* W  = (const float*)d_in[2];
    const float* b  = (const float*)d_in[3];
    float* out = (float*)d_out;

    // ws (~25 MB of 256 MB pool) — no overlays, all buffers distinct
    char* ws = (char*)d_ws;
    size_t o = 0;
    int*      tmp   = (int*)(ws + o);      o += (size_t)NBIN * CAPT * 4;   o = (o + 255) & ~(size_t)255;
    unsigned* hu    = (unsigned*)(ws + o); o += (size_t)NN * 16 * 4;       o = (o + 255) & ~(size_t)255;
    int*      cfill = (int*)(ws + o);      o += (size_t)NCHK * NBIN * 4;   o = (o + 255) & ~(size_t)255;
    int*      deg   = (int*)(ws + o);

    k_bin<<<NCHK, 1024, 0, stream>>>(ei, tmp, cfill);
    k_degLin<<<NBIN, 1024, 0, stream>>>(cfill, tmp, x, W, deg, hu);
    k_placeAgg<<<NBIN, AGG_T, 0, stream>>>(cfill, tmp, deg, (const uint4*)hu, b, out);
}